// Round 11
// baseline (250.822 us; speedup 1.0000x reference)
//
#include <hip/hip_runtime.h>
#include <hip/hip_bf16.h>
#include <stdint.h>

// B=1024, D_IN=2048, D_H=4096, D_OUT=2048, D_INT=1024
// Algebra: W_ff = H_R Z H_C, Z = gather(t,Pi,GG).reshape(R,C).
// x@W_ff^T = rowWHT_R( (rowWHT_C(x)) @ Z^T ) * sc  — WHTs act on activations.

typedef __attribute__((ext_vector_type(8))) short bf16x8;
typedef __attribute__((ext_vector_type(8))) short short8;
typedef __attribute__((ext_vector_type(4))) float f32x4;

__device__ __forceinline__ ushort f2bf(float f) {
  union { float f; uint32_t u; } v; v.f = f;
  return (ushort)((v.u + 0x7FFFu + ((v.u >> 16) & 1u)) >> 16);
}
__device__ __forceinline__ float bf2f(ushort u) {
  union { uint32_t u; float f; } v; v.u = (uint32_t)u << 16; return v.f;
}

__device__ __forceinline__ void gload_lds16(const void* g, void* l) {
  __builtin_amdgcn_global_load_lds(
      (const __attribute__((address_space(1))) void*)g,
      (__attribute__((address_space(3))) void*)l, 16, 0, 0);
}

__device__ __forceinline__ void wait_vm8()  { asm volatile("s_waitcnt vmcnt(8)"  ::: "memory"); }
__device__ __forceinline__ void wait_vm4()  { asm volatile("s_waitcnt vmcnt(4)"  ::: "memory"); }
__device__ __forceinline__ void wait_vm0()  { asm volatile("s_waitcnt vmcnt(0)"  ::: "memory"); }
__device__ __forceinline__ void wait_lgkm0(){ asm volatile("s_waitcnt lgkmcnt(0)" ::: "memory"); }
__device__ __forceinline__ void barrier_raw(){ asm volatile("s_barrier" ::: "memory"); }

template <int NN>
__device__ __forceinline__ void wht_inreg(float* v) {
#pragma unroll
  for (int h = 1; h < NN; h <<= 1)
#pragma unroll
    for (int g = 0; g < NN; g += (h << 1))
#pragma unroll
      for (int k = 0; k < h; ++k) {
        float a = v[g + k], b = v[g + k + h];
        v[g + k] = a + b; v[g + k + h] = a - b;
      }
}

// ---------------- cvt_stream: grid-stride f32->bf16 for x, W1_0, W2_0.
// Zero LDS, 2048 resident blocks -> m13-style streaming regime.
__global__ __launch_bounds__(256) void cvt_stream(
    const float4* __restrict__ x4, ushort4* __restrict__ xb4,
    const float4* __restrict__ W10, ushort4* __restrict__ W1b4,
    const float4* __restrict__ W20, ushort4* __restrict__ W2b4) {
  const int gid = blockIdx.x * 256 + threadIdx.x;
  const int stride = 2048 * 256;
  // x: 524288 float4 (exactly one per thread)
  {
    float4 v = x4[gid];
    ushort4 o;
    o.x = f2bf(v.x); o.y = f2bf(v.y); o.z = f2bf(v.z); o.w = f2bf(v.w);
    xb4[gid] = o;
  }
  // W1_0: 2097152 float4 (4 iters)
#pragma unroll
  for (int it = 0; it < 4; ++it) {
    int i = gid + it * stride;
    float4 v = W10[i];
    ushort4 o;
    o.x = f2bf(v.x); o.y = f2bf(v.y); o.z = f2bf(v.z); o.w = f2bf(v.w);
    W1b4[i] = o;
  }
  // W2_0: 2097152 float4 (4 iters)
#pragma unroll
  for (int it = 0; it < 4; ++it) {
    int i = gid + it * stride;
    float4 v = W20[i];
    ushort4 o;
    o.x = f2bf(v.x); o.y = f2bf(v.y); o.z = f2bf(v.z); o.w = f2bf(v.w);
    W2b4[i] = o;
  }
}

// ---------------- prep_small: blocks 0-1 make t1/t2; blocks 2-3 bias fastfoods.
__global__ __launch_bounds__(256) void prep_small(
    const float* __restrict__ V,
    const float* __restrict__ BBW1, const float* __restrict__ BBW2,
    float* __restrict__ t1, float* __restrict__ t2,
    const float* __restrict__ BBb1, const int* __restrict__ Pib1,
    const float* __restrict__ GGb1, const float* __restrict__ b10,
    const float* __restrict__ BBb2, const int* __restrict__ Pib2,
    const float* __restrict__ GGb2, const float* __restrict__ b20,
    float* __restrict__ ob1, float* __restrict__ ob2) {
  __shared__ float ts[1024];
  __shared__ float zs[4096];
  __shared__ float red[4];
  const int bid = blockIdx.x;
  const int tid = threadIdx.x;

  if (bid < 2) {                          // make t
    const int which = bid;
    const float* BB = which ? BBW2 : BBW1;
    float* t = which ? t2 : t1;
    for (int i = tid; i < 1024; i += 256) ts[i] = BB[i] * V[i];
    for (int st = 0; st < 10; ++st) {
      int half = 1 << st;
      __syncthreads();
      for (int j = tid; j < 512; j += 256) {
        int p = ((j >> st) << (st + 1)) | (j & (half - 1));
        float a = ts[p], b = ts[p + half];
        ts[p] = a + b; ts[p + half] = a - b;
      }
    }
    __syncthreads();
    for (int i = tid; i < 1024; i += 256) t[i] = ts[i];
    return;
  }

  {                                       // bias fastfood
    const int which = bid - 2;
    const int L = which ? 2048 : 4096;
    const float* BB = which ? BBb2 : BBb1;
    const int* Pi = which ? Pib2 : Pib1;
    const float* GG = which ? GGb2 : GGb1;
    const float* b0 = which ? b20 : b10;
    float* ob = which ? ob2 : ob1;

    for (int i = tid; i < 1024; i += 256) ts[i] = BB[i] * V[i];
    for (int st = 0; st < 10; ++st) {
      int half = 1 << st;
      __syncthreads();
      for (int j = tid; j < 512; j += 256) {
        int p = ((j >> st) << (st + 1)) | (j & (half - 1));
        float a = ts[p], b = ts[p + half];
        ts[p] = a + b; ts[p + half] = a - b;
      }
    }
    __syncthreads();
    float gsum = 0.f;
    for (int i = tid; i < L; i += 256) {
      int pi = Pi[i];
      float g = GG[i];
      gsum += g * g;
      zs[i] = ts[pi & 1023] * g;
    }
    for (int o = 32; o > 0; o >>= 1) gsum += __shfl_down(gsum, o);
    if ((tid & 63) == 0) red[tid >> 6] = gsum;
    __syncthreads();
    float ssum = red[0] + red[1] + red[2] + red[3];
    for (int st = 0; (1 << st) < L; ++st) {
      int half = 1 << st;
      __syncthreads();
      for (int j = tid; j < (L >> 1); j += 256) {
        int p = ((j >> st) << (st + 1)) | (j & (half - 1));
        float a = zs[p], b = zs[p + half];
        zs[p] = a + b; zs[p + half] = a - b;
      }
    }
    __syncthreads();
    float scale = rsqrtf((float)L * ssum);
    for (int i = tid; i < L; i += 256) ob[i] = b0[i] + zs[i] * scale;
  }
}

// ---------------- build_z: Z = bf16(t[Pi&1023]*GG) + per-block sum(G^2). [r9-proven]
__global__ __launch_bounds__(256) void build_z(
    const int* __restrict__ Pi, const float* __restrict__ GG,
    const float* __restrict__ t, ushort* __restrict__ z,
    float* __restrict__ partials) {
  __shared__ float ts[1024];
  __shared__ float red[4];
  const int tid = threadIdx.x;
  const size_t base = (size_t)blockIdx.x << 13;

  for (int i = tid; i < 1024; i += 256) ts[i] = t[i];
  __syncthreads();

  const int4* Pi4 = (const int4*)(Pi + base);
  const float4* GG4 = (const float4*)(GG + base);
  float gsum = 0.f;
#pragma unroll
  for (int q = 0; q < 4; ++q) {
    const int4 pa = Pi4[(q << 9) + (tid << 1)];
    const int4 pb = Pi4[(q << 9) + (tid << 1) + 1];
    const float4 ga = GG4[(q << 9) + (tid << 1)];
    const float4 gb = GG4[(q << 9) + (tid << 1) + 1];
    gsum += ga.x * ga.x + ga.y * ga.y + ga.z * ga.z + ga.w * ga.w
          + gb.x * gb.x + gb.y * gb.y + gb.z * gb.z + gb.w * gb.w;
    short8 o;
    o[0] = (short)f2bf(ts[pa.x & 1023] * ga.x);
    o[1] = (short)f2bf(ts[pa.y & 1023] * ga.y);
    o[2] = (short)f2bf(ts[pa.z & 1023] * ga.z);
    o[3] = (short)f2bf(ts[pa.w & 1023] * ga.w);
    o[4] = (short)f2bf(ts[pb.x & 1023] * gb.x);
    o[5] = (short)f2bf(ts[pb.y & 1023] * gb.y);
    o[6] = (short)f2bf(ts[pb.z & 1023] * gb.z);
    o[7] = (short)f2bf(ts[pb.w & 1023] * gb.w);
    *(short8*)(z + base + (q << 11) + (tid << 3)) = o;
  }
  for (int o2 = 32; o2 > 0; o2 >>= 1) gsum += __shfl_down(gsum, o2);
  if ((tid & 63) == 0) red[tid >> 6] = gsum;
  __syncthreads();
  if (tid == 0) partials[blockIdx.x] = red[0] + red[1] + red[2] + red[3];
}

// ---------------- rowwht2048: per-row 2048-pt WHT, 8 rows/block, 32 thr/row.
// INMODE 0: f32 input; INMODE 2: sum of two f32 planes. Output bf16.
template <int INMODE, bool SCALE>
__global__ __launch_bounds__(256) void rowwht2048(
    const float* __restrict__ in0, const float* __restrict__ in1,
    ushort* __restrict__ outp, const float* __restrict__ partials) {
  __shared__ ushort tile[8][2176];
  __shared__ float red[4];
  const int tid = threadIdx.x;
  const int r = tid >> 5;
  const int k = tid & 31;
  const int row = (blockIdx.x << 3) + r;
  if constexpr (SCALE) {
    float s = partials[tid] + partials[tid + 256] + partials[tid + 512] + partials[tid + 768];
    for (int o = 32; o > 0; o >>= 1) s += __shfl_down(s, o);
    if ((tid & 63) == 0) red[tid >> 6] = s;
  }
  float v[64];
  {
    const float4* ip = (const float4*)(in0 + ((size_t)row << 11) + (k << 6));
#pragma unroll
    for (int j = 0; j < 16; ++j) {
      float4 d = ip[j];
      v[4 * j] = d.x; v[4 * j + 1] = d.y; v[4 * j + 2] = d.z; v[4 * j + 3] = d.w;
    }
    if constexpr (INMODE == 2) {
      const float4* iq = (const float4*)(in1 + ((size_t)row << 11) + (k << 6));
#pragma unroll
      for (int j = 0; j < 16; ++j) {
        float4 d = iq[j];
        v[4 * j] += d.x; v[4 * j + 1] += d.y; v[4 * j + 2] += d.z; v[4 * j + 3] += d.w;
      }
    }
  }
  wht_inreg<64>(v);
  {
    ushort* tp = &tile[r][68 * k];
#pragma unroll
    for (int j = 0; j < 16; ++j) {
      ushort4 u;
      u.x = f2bf(v[4 * j]); u.y = f2bf(v[4 * j + 1]);
      u.z = f2bf(v[4 * j + 2]); u.w = f2bf(v[4 * j + 3]);
      *(ushort4*)(tp + (j << 2)) = u;
    }
  }
  __syncthreads();
  float sc = 1.f;
  if constexpr (SCALE) sc = rsqrtf(8388608.f * (red[0] + red[1] + red[2] + red[3]));

  float va[32], vb[32];
#pragma unroll
  for (int m = 0; m < 32; ++m) {
    ushort2 u = *(const ushort2*)&tile[r][(k << 1) + 68 * m];
    va[m] = bf2f(u.x); vb[m] = bf2f(u.y);
  }
  wht_inreg<32>(va); wht_inreg<32>(vb);
  ushort* op = outp + ((size_t)row << 11) + (k << 1);
#pragma unroll
  for (int m = 0; m < 32; ++m) {
    ushort2 o; o.x = f2bf(va[m] * sc); o.y = f2bf(vb[m] * sc);
    *(ushort2*)(op + (m << 6)) = o;
  }
}

// ---------------- rowwht4096: per-row 4096-pt WHT, 4 rows/block. [r9-proven]
template <bool SCALE>
__global__ __launch_bounds__(256) void rowwht4096(
    const ushort* __restrict__ in, ushort* __restrict__ outp,
    const float* __restrict__ partials) {
  __shared__ ushort tile[4][4352];
  __shared__ float red[4];
  const int tid = threadIdx.x;
  const int r = tid >> 6;
  const int k = tid & 63;
  const int row = (blockIdx.x << 2) + r;
  if constexpr (SCALE) {
    float s = partials[tid] + partials[tid + 256] + partials[tid + 512] + partials[tid + 768];
    for (int o = 32; o > 0; o >>= 1) s += __shfl_down(s, o);
    if ((tid & 63) == 0) red[tid >> 6] = s;
  }
  float v[64];
  const ushort* ip = in + ((size_t)row << 12) + (k << 6);
#pragma unroll
  for (int j = 0; j < 8; ++j) {
    short8 d = *(const short8*)(ip + (j << 3));
#pragma unroll
    for (int e = 0; e < 8; ++e) v[8 * j + e] = bf2f((ushort)d[e]);
  }
  wht_inreg<64>(v);
  {
    ushort* tp = &tile[r][68 * k];
#pragma unroll
    for (int j = 0; j < 16; ++j) {
      ushort4 u;
      u.x = f2bf(v[4 * j]); u.y = f2bf(v[4 * j + 1]);
      u.z = f2bf(v[4 * j + 2]); u.w = f2bf(v[4 * j + 3]);
      *(ushort4*)(tp + (j << 2)) = u;
    }
  }
  __syncthreads();
  float sc = 1.f;
  if constexpr (SCALE) sc = rsqrtf(8388608.f * (red[0] + red[1] + red[2] + red[3]));

  float w[64];
#pragma unroll
  for (int m = 0; m < 64; ++m) w[m] = bf2f(tile[r][k + 68 * m]);
  wht_inreg<64>(w);
  ushort* op = outp + ((size_t)row << 12) + k;
#pragma unroll
  for (int m = 0; m < 64; ++m) op[m << 6] = f2bf(w[m] * sc);
}

// ---------------- gemm8: C = A*B^T, 128x128 tile, BK=64, 8 waves (2x4).
// 4-buffer LDS, 3-deep prefetch, counted vmcnt, raw s_barrier, XOR swizzle.
// XCD-chunked block swizzle on (bx,by) within each bz plane (bijective).
// EPI 1: f32 -> plane Cf0/Cf1 by bz; EPI 2: bf16(acc); EPI 3: bf16(relu(acc+bias+Waux)).
template <int EPI, int NT, int GX, int GY>
__global__ __launch_bounds__(512) void gemm8(
    const ushort* __restrict__ A, const ushort* __restrict__ B,
    const float* __restrict__ bias, const ushort* __restrict__ Waux,
    ushort* __restrict__ Cb, float* __restrict__ Cf0, float* __restrict__ Cf1,
    int M, int N, int K) {
  __shared__ ushort As[4][8192];
  __shared__ ushort Bs[4][8192];
  // XCD swizzle: chunk the linear xy-block id so each XCD gets contiguous tiles
  constexpr int NXY = GX * GY;
  const int lxy = blockIdx.x + GX * blockIdx.y;
  const int sw = (lxy & 7) * (NXY / 8) + (lxy >> 3);
  const int bxs = sw % GX, bys = sw / GX;
  const int tid = threadIdx.x;
  const int w = tid >> 6, l = tid & 63;
  const int wr = w >> 2, wc = w & 3;
  const int brow = bys << 7, bcol = bxs << 7;
  const int srow = tid >> 3;
  const int sg = tid & 7;
  const int csrc = (sg ^ (srow & 7)) << 3;
  const int l15 = l & 15;
  const int kb = blockIdx.z * (NT << 6);
  f32x4 acc[4][2] = {};

  const ushort* pa0 = A + (size_t)(brow + srow) * K + kb + csrc;
  const ushort* pb0 = B + (size_t)(bcol + srow) * K + kb + csrc;
  const size_t K64 = (size_t)K << 6;

#define STAGE(buf, tt)                                                \
  {                                                                   \
    const ushort* qa = pa0 + ((tt) << 6);                             \
    const ushort* qb = pb0 + ((tt) << 6);                             \
    gload_lds16(qa,       (char*)As[buf] + (tid << 4));               \
    gload_lds16(qa + K64, (char*)As[buf] + (tid << 4) + 8192);        \
    gload_lds16(qb,       (char*)Bs[buf] + (tid << 4));               \
    gload_lds16(qb + K64, (char*)Bs[buf] + (tid << 4) + 8192);        \
  }

  STAGE(0, 0); STAGE(1, 1); STAGE(2, 2);
  for (int t = 0; t < NT; ++t) {
    if (t < NT - 2) wait_vm8();
    else if (t == NT - 2) wait_vm4();
    else wait_vm0();
    barrier_raw();
    if (t + 3 < NT) STAGE((t + 3) & 3, t + 3);
    const ushort* Acur = As[t & 3];
    const ushort* Bcur = Bs[t & 3];
    bf16x8 af[2][4], bfr[2][2];
#pragma unroll
    for (int kk = 0; kk < 2; ++kk) {
      int c8 = (kk << 2) + (l >> 4);
#pragma unroll
      for (int m = 0; m < 4; ++m) {
        int ra = (wr << 6) + (m << 4) + l15;
        af[kk][m] = *(const bf16x8*)&Acur[(ra << 6) + ((c8 ^ (ra & 7)) << 3)];
      }
#pragma unroll
      for (int n = 0; n < 2; ++n) {
        int rb = (wc << 5) + (n << 4) + l15;
        bfr[kk][n] = *(const bf16x8*)&Bcur[(rb << 6) + ((c8 ^ (rb & 7)) << 3)];
      }
    }
    wait_lgkm0();
#pragma unroll
    for (int kk = 0; kk < 2; ++kk)
#pragma unroll
      for (int m = 0; m < 4; ++m)
#pragma unroll
        for (int n = 0; n < 2; ++n)
          acc[m][n] = __builtin_amdgcn_mfma_f32_16x16x32_bf16(af[kk][m], bfr[kk][n], acc[m][n], 0, 0, 0);
  }
#undef STAGE

  float* outp = (EPI == 1) ? (blockIdx.z ? Cf1 : Cf0) : nullptr;
#pragma unroll
  for (int n = 0; n < 2; ++n) {
    int col = bcol + (wc << 5) + (n << 4) + l15;
    float bv = (EPI == 3) ? bias[col] : 0.f;
#pragma unroll
    for (int m = 0; m < 4; ++m) {
      int row0 = brow + (wr << 6) + (m << 4) + ((l >> 4) << 2);
#pragma unroll
      for (int j = 0; j < 4; ++j) {
        size_t idx = (size_t)(row0 + j) * N + col;
        if (EPI == 1) {
          outp[idx] = acc[m][n][j];
        } else if (EPI == 2) {
          Cb[idx] = f2bf(acc[m][n][j]);
        } else {
          float vv = acc[m][n][j] + bv + bf2f(Waux[idx]);
          Cb[idx] = f2bf(fmaxf(vv, 0.f));
        }
      }
    }
  }
}

// ---------------- out = PP0 + PP1 + w2(bf16) + b2   (1024x2048 f32)
__global__ __launch_bounds__(256) void reduce_out(
    const float4* __restrict__ PP0, const float4* __restrict__ PP1,
    const ushort4* __restrict__ w2, const float* __restrict__ b2,
    float4* __restrict__ out) {
  int i = blockIdx.x * 256 + threadIdx.x;     // 524288 f4
  float4 a = PP0[i], b = PP1[i];
  ushort4 wz = w2[i];
  const float4 bb = *(const float4*)(b2 + ((i & 511) << 2));
  float4 o;
  o.x = a.x + b.x + bf2f(wz.x) + bb.x;
  o.y = a.y + b.y + bf2f(wz.y) + bb.y;
  o.z = a.z + b.z + bf2f(wz.z) + bb.z;
  o.w = a.w + b.w + bf2f(wz.w) + bb.w;
  out[i] = o;
}

extern "C" void kernel_launch(void* const* d_in, const int* in_sizes, int n_in,
                              void* d_out, int out_size, void* d_ws, size_t ws_size,
                              hipStream_t stream) {
  const float* x     = (const float*)d_in[0];
  const float* V     = (const float*)d_in[1];
  const float* W1_0  = (const float*)d_in[2];
  const float* b1_0  = (const float*)d_in[3];
  const float* W2_0  = (const float*)d_in[4];
  const float* b2_0  = (const float*)d_in[5];
  const float* BB_W1 = (const float*)d_in[6];
  const int*   Pi_W1 = (const int*)d_in[7];
  const float* GG_W1 = (const float*)d_in[8];
  const float* BB_b1 = (const float*)d_in[9];
  const int*   Pi_b1 = (const int*)d_in[10];
  const float* GG_b1 = (const float*)d_in[11];
  const float* BB_W2 = (const float*)d_in[12];
  const int*   Pi_W2 = (const int*)d_in[13];
  const float* GG_W2 = (const float*)d_in[14];
  const float* BB_b2 = (const float*)d_in[15];
  const int*   Pi_b2 = (const int*)d_in[16];
  const float* GG_b2 = (const float*)d_in[17];
  float* out = (float*)d_out;

  const size_t MB = 1048576ull;
  char* ws = (char*)d_ws;
  // Layout (72 MB + 40 KB; lifetimes disjoint per dispatch order):
  ushort* W2b = (ushort*)(ws);                 // @0  d1..d11
  ushort* W1b = (ushort*)(ws + 16 * MB);       // @16 d1..d6
  ushort* hH  = (ushort*)(ws + 16 * MB);       // @16 d8..d9 (8MB)
  ushort* w2  = (ushort*)(ws + 24 * MB);       // @24 d10..d12 (4MB)
  ushort* Y   = (ushort*)(ws + 32 * MB);       // @32 Y1 d3..d4, Y2 d7..d9 (16MB)
  float*  PP0 = (float*)(ws + 32 * MB);        // @32 d11..d12 (8MB)
  float*  PP1 = (float*)(ws + 40 * MB);        // @40 d11..d12 (8MB)
  ushort* hb  = (ushort*)(ws + 48 * MB);       // @48 d6..d11 (8MB)
  ushort* v1b = (ushort*)(ws + 56 * MB);       // @56 d4..d6 (8MB)
  float*  P0  = (float*)(ws + 56 * MB);        // @56 d9..d10 (8MB)
  ushort* xb  = (ushort*)(ws + 64 * MB);       // @64 d1..d6 (4MB)
  float*  P1  = (float*)(ws + 64 * MB);        // @64 d9..d10 (8MB, over xb+ub dead)
  ushort* ub  = (ushort*)(ws + 68 * MB);       // @68 d2..d4 (4MB)
  char*   S   = ws + 72 * MB;
  float* t1     = (float*)(S);
  float* t2     = (float*)(S + 4096);
  float* b1     = (float*)(S + 8192);
  float* b2     = (float*)(S + 8192 + 16384);
  float* parts1 = (float*)(S + 8192 + 16384 + 8192);
  float* parts2 = (float*)(S + 8192 + 16384 + 8192 + 4096);

  // d0: t1/t2 + bias fastfoods (tiny)
  prep_small<<<4, 256, 0, stream>>>(V, BB_W1, BB_W2, t1, t2,
                                    BB_b1, Pi_b1, GG_b1, b1_0,
                                    BB_b2, Pi_b2, GG_b2, b2_0, b1, b2);
  // d1: grid-stride cvt x/W1_0/W2_0 -> bf16
  cvt_stream<<<2048, 256, 0, stream>>>((const float4*)x, (ushort4*)xb,
                                       (const float4*)W1_0, (ushort4*)W1b,
                                       (const float4*)W2_0, (ushort4*)W2b);
  // d2: u = rowWHT_2048(x)
  rowwht2048<0, false><<<128, 256, 0, stream>>>(x, nullptr, ub, nullptr);
  // d3: Y1 = gather
  build_z<<<1024, 256, 0, stream>>>(Pi_W1, GG_W1, t1, Y, parts1);
  // d4: v1 = u @ Y1^T  (bf16)
  gemm8<2, 32, 32, 8><<<dim3(32, 8, 1), 512, 0, stream>>>(ub, Y, nullptr, nullptr, v1b, nullptr, nullptr, 1024, 4096, 2048);
  // d5: w1 = sc1 * rowWHT_4096(v1)  (in-place)
  rowwht4096<true><<<256, 256, 0, stream>>>(v1b, v1b, parts1);
  // d6: h = relu(x@W1b^T + w1 + b1)
  gemm8<3, 32, 32, 8><<<dim3(32, 8, 1), 512, 0, stream>>>(xb, W1b, b1, v1b, hb, nullptr, nullptr, 1024, 4096, 2048);
  // d7: Y2 = gather
  build_z<<<1024, 256, 0, stream>>>(Pi_W2, GG_W2, t2, Y, parts2);
  // d8: hH = rowWHT_4096(h)
  rowwht4096<false><<<256, 256, 0, stream>>>(hb, hH, nullptr);
  // d9: v2 planes = hH @ Y2^T  (split-K2, f32 planes)
  gemm8<1, 32, 16, 8><<<dim3(16, 8, 2), 512, 0, stream>>>(hH, Y, nullptr, nullptr, nullptr, P0, P1, 1024, 2048, 4096);
  // d10: w2 = sc2 * rowWHT_2048(P0+P1)
  rowwht2048<2, true><<<128, 256, 0, stream>>>(P0, P1, w2, parts2);
  // d11: out planes = h @ W2b^T  (split-K2, f32 planes)
  gemm8<1, 32, 16, 8><<<dim3(16, 8, 2), 512, 0, stream>>>(hb, W2b, nullptr, nullptr, nullptr, PP0, PP1, 1024, 2048, 4096);
  // d12: out = PP0 + PP1 + w2 + b2
  reduce_out<<<2048, 256, 0, stream>>>((const float4*)PP0, (const float4*)PP1,
                                       (const ushort4*)w2, b2, (float4*)out);
}

// Round 12
// 157.593 us; speedup vs baseline: 1.5916x; 1.5916x over previous
//
#include <hip/hip_runtime.h>
#include <hip/hip_bf16.h>
#include <stdint.h>

// B=1024, D_IN=2048, D_H=4096, D_OUT=2048, D_INT=1024
// r8 skeleton (best measured: 171us) + split-K GEMMs at 2 blocks/CU.

typedef __attribute__((ext_vector_type(8))) short bf16x8;   // 8 bf16 (4 VGPRs)
typedef __attribute__((ext_vector_type(8))) short short8;
typedef __attribute__((ext_vector_type(4))) float f32x4;

__device__ __forceinline__ ushort f2bf(float f) {           // RNE f32->bf16
  union { float f; uint32_t u; } v; v.f = f;
  return (ushort)((v.u + 0x7FFFu + ((v.u >> 16) & 1u)) >> 16);
}
__device__ __forceinline__ float bf2f(ushort u) {
  union { uint32_t u; float f; } v; v.u = (uint32_t)u << 16; return v.f;
}

__device__ __forceinline__ void gload_lds16(const void* g, void* l) {
  __builtin_amdgcn_global_load_lds(
      (const __attribute__((address_space(1))) void*)g,
      (__attribute__((address_space(3))) void*)l, 16, 0, 0);
}

__device__ __forceinline__ void wait_vm0()  { asm volatile("s_waitcnt vmcnt(0)"  ::: "memory"); }
__device__ __forceinline__ void wait_lgkm0(){ asm volatile("s_waitcnt lgkmcnt(0)" ::: "memory"); }
__device__ __forceinline__ void barrier_raw(){ asm volatile("s_barrier" ::: "memory"); }

template <int NN>
__device__ __forceinline__ void wht_inreg(float* v) {
#pragma unroll
  for (int h = 1; h < NN; h <<= 1)
#pragma unroll
    for (int g = 0; g < NN; g += (h << 1))
#pragma unroll
      for (int k = 0; k < h; ++k) {
        float a = v[g + k], b = v[g + k + h];
        v[g + k] = a + b; v[g + k + h] = a - b;
      }
}

// ---------------- prep: fused  (a) x f32->bf16 cvt [blocks 0..2047]
//                               (b) t = WHT_1024(BB*V) for W1/W2 [2048..2049]
//                               (c) full bias fastfood b1/b2 [2050..2051]
__global__ __launch_bounds__(256) void prep(
    const float4* __restrict__ x4, ushort4* __restrict__ xb4,
    const float* __restrict__ V,
    const float* __restrict__ BBW1, const float* __restrict__ BBW2,
    float* __restrict__ t1, float* __restrict__ t2,
    const float* __restrict__ BBb1, const int* __restrict__ Pib1,
    const float* __restrict__ GGb1, const float* __restrict__ b10,
    const float* __restrict__ BBb2, const int* __restrict__ Pib2,
    const float* __restrict__ GGb2, const float* __restrict__ b20,
    float* __restrict__ ob1, float* __restrict__ ob2) {
  __shared__ float ts[1024];
  __shared__ float zs[4096];
  __shared__ float red[4];
  const int bid = blockIdx.x;
  const int tid = threadIdx.x;

  if (bid < 2048) {                       // role (a): cvt
    int i = bid * 256 + tid;
    float4 v = x4[i];
    ushort4 o;
    o.x = f2bf(v.x); o.y = f2bf(v.y); o.z = f2bf(v.z); o.w = f2bf(v.w);
    xb4[i] = o;
    return;
  }

  if (bid < 2050) {                       // role (b): make_t
    const int which = bid - 2048;
    const float* BB = which ? BBW2 : BBW1;
    float* t = which ? t2 : t1;
    for (int i = tid; i < 1024; i += 256) ts[i] = BB[i] * V[i];
    for (int st = 0; st < 10; ++st) {
      int half = 1 << st;
      __syncthreads();
      for (int j = tid; j < 512; j += 256) {
        int p = ((j >> st) << (st + 1)) | (j & (half - 1));
        float a = ts[p], b = ts[p + half];
        ts[p] = a + b; ts[p + half] = a - b;
      }
    }
    __syncthreads();
    for (int i = tid; i < 1024; i += 256) t[i] = ts[i];
    return;
  }

  // role (c): bias fastfood
  {
    const int which = bid - 2050;
    const int L = which ? 2048 : 4096;
    const float* BB = which ? BBb2 : BBb1;
    const int* Pi = which ? Pib2 : Pib1;
    const float* GG = which ? GGb2 : GGb1;
    const float* b0 = which ? b20 : b10;
    float* ob = which ? ob2 : ob1;

    for (int i = tid; i < 1024; i += 256) ts[i] = BB[i] * V[i];
    for (int st = 0; st < 10; ++st) {
      int half = 1 << st;
      __syncthreads();
      for (int j = tid; j < 512; j += 256) {
        int p = ((j >> st) << (st + 1)) | (j & (half - 1));
        float a = ts[p], b = ts[p + half];
        ts[p] = a + b; ts[p + half] = a - b;
      }
    }
    __syncthreads();
    float gsum = 0.f;
    for (int i = tid; i < L; i += 256) {
      int pi = Pi[i];
      float g = GG[i];
      gsum += g * g;
      zs[i] = ts[pi & 1023] * g;
    }
    for (int o = 32; o > 0; o >>= 1) gsum += __shfl_down(gsum, o);
    if ((tid & 63) == 0) red[tid >> 6] = gsum;
    __syncthreads();
    float ssum = red[0] + red[1] + red[2] + red[3];
    for (int st = 0; (1 << st) < L; ++st) {
      int half = 1 << st;
      __syncthreads();
      for (int j = tid; j < (L >> 1); j += 256) {
        int p = ((j >> st) << (st + 1)) | (j & (half - 1));
        float a = zs[p], b = zs[p + half];
        zs[p] = a + b; zs[p + half] = a - b;
      }
    }
    __syncthreads();
    float scale = rsqrtf((float)L * ssum);
    for (int i = tid; i < L; i += 256) ob[i] = b0[i] + zs[i] * scale;
  }
}

// ---------------- pass 1 (both weights): z = t[Pi&1023]*GG, WHT_8192 on
// contiguous 8192-chunks (bits 0..12) via radix 32(b3-7)/32(b8-12)/8(b0-2)
// register passes; skewed f32 LDS slot = i + (i>>5) keeps all phases <=2-way.
// [r3/r8-proven]
__global__ __launch_bounds__(256) void ff_pass1(
    const int* __restrict__ Pi1, const float* __restrict__ GG1,
    const int* __restrict__ Pi2, const float* __restrict__ GG2,
    const float* __restrict__ t1, const float* __restrict__ t2,
    ushort* __restrict__ inter1, ushort* __restrict__ inter2,
    float* __restrict__ partials) {
  __shared__ float ts[1024];
  __shared__ float zs[8448];        // 8192 + skew
  __shared__ float red[4];
  int tid = threadIdx.x;
  int wsel = blockIdx.x >> 10;
  int blk = blockIdx.x & 1023;
  const int* Pi = wsel ? Pi2 : Pi1;
  const float* GG = wsel ? GG2 : GG1;
  const float* t = wsel ? t2 : t1;
  ushort* inter = wsel ? inter2 : inter1;
  size_t base = (size_t)blk * 8192;

  for (int i = tid; i < 1024; i += 256) ts[i] = t[i];
  __syncthreads();

  const int4* Pi4 = (const int4*)(Pi + base);
  const float4* GG4 = (const float4*)(GG + base);
  float gsum = 0.f;
#pragma unroll
  for (int q = 0; q < 8; ++q) {
    int u = (q << 8) + tid;          // 0..2047
    int4 p4 = Pi4[u];
    float4 g4 = GG4[u];
    gsum += g4.x * g4.x + g4.y * g4.y + g4.z * g4.z + g4.w * g4.w;
    int i0 = u << 2;
    float4 z;
    z.x = ts[p4.x & 1023] * g4.x;
    z.y = ts[p4.y & 1023] * g4.y;
    z.z = ts[p4.z & 1023] * g4.z;
    z.w = ts[p4.w & 1023] * g4.w;
    *(float4*)&zs[i0 + (i0 >> 5)] = z;
  }
  for (int o = 32; o > 0; o >>= 1) gsum += __shfl_down(gsum, o);
  if ((tid & 63) == 0) red[tid >> 6] = gsum;
  __syncthreads();
  if (tid == 0) partials[blockIdx.x] = red[0] + red[1] + red[2] + red[3];

  float v[32];
  // pass A: bits 3-7
  {
    int o = (tid & 7) | ((tid >> 3) << 8);
#pragma unroll
    for (int r = 0; r < 32; ++r) { int i = o + (r << 3); v[r] = zs[i + (i >> 5)]; }
    wht_inreg<32>(v);
#pragma unroll
    for (int r = 0; r < 32; ++r) { int i = o + (r << 3); zs[i + (i >> 5)] = v[r]; }
  }
  __syncthreads();
  // pass B: bits 8-12
  {
#pragma unroll
    for (int r = 0; r < 32; ++r) { int i = tid | (r << 8); v[r] = zs[i + (i >> 5)]; }
    wht_inreg<32>(v);
#pragma unroll
    for (int r = 0; r < 32; ++r) { int i = tid | (r << 8); zs[i + (i >> 5)] = v[r]; }
  }
  __syncthreads();
  // pass C: bits 0-2 (4 runs of 8) + coalesced short8 stores
  {
    int tp = ((tid & 63) << 3) | ((tid >> 6) << 11);
#pragma unroll
    for (int j = 0; j < 4; ++j)
#pragma unroll
      for (int k = 0; k < 8; ++k) { int i = tp + (j << 9) + k; v[(j << 3) + k] = zs[i + (i >> 5)]; }
#pragma unroll
    for (int j = 0; j < 4; ++j) wht_inreg<8>(v + (j << 3));
#pragma unroll
    for (int j = 0; j < 4; ++j) {
      short8 s;
#pragma unroll
      for (int k = 0; k < 8; ++k) s[k] = (short)f2bf(v[(j << 3) + k]);
      *(short8*)(inter + base + tp + (j << 9)) = s;
    }
  }
}

// ---------------- pass 2 (both weights): WHT_1024 over h (global bits 13..22,
// stride 8192) on a [1024 rows x 64 cols] bf16 LDS tile. [r8-proven]
__global__ __launch_bounds__(512) void ff_pass2(
    const ushort* __restrict__ inter1, const ushort* __restrict__ inter2,
    const float* __restrict__ W01, const float* __restrict__ W02,
    const float* __restrict__ partials,
    ushort* __restrict__ W1b, ushort* __restrict__ W2b) {
  __shared__ ushort tile[65536];          // 128 KB
  __shared__ float red[8];
  const int tid = threadIdx.x;
  const int wsel = blockIdx.x >> 7;
  const int cb = (blockIdx.x & 127) << 6;
  const ushort* __restrict__ inter = wsel ? inter2 : inter1;
  const float* __restrict__ W0 = wsel ? W02 : W01;
  ushort* __restrict__ Wb = wsel ? W2b : W1b;
  char* tb = (char*)tile;

  float s = partials[(wsel << 10) + tid] + partials[(wsel << 10) + tid + 512];
  for (int o = 32; o > 0; o >>= 1) s += __shfl_down(s, o);
  if ((tid & 63) == 0) red[tid >> 6] = s;

  // phase 1: coalesced row loads (128 B/lane/row), swizzled LDS stores
#pragma unroll
  for (int h = 0; h < 2; ++h) {
    int r = tid + (h << 9);
    const ushort* gp = inter + ((size_t)r << 13) + cb;
#pragma unroll
    for (int j = 0; j < 8; ++j) {
      short8 d = *(const short8*)(gp + (j << 3));
      *(short8*)(tb + (r << 7) + ((j ^ (r & 7)) << 4)) = d;
    }
  }
  __syncthreads();
  float ssum = 0.f;
#pragma unroll
  for (int k = 0; k < 8; ++k) ssum += red[k];
  const float sc = rsqrtf(8388608.f * ssum);

  const int p = tid & 31;                 // col pair 2p
  const int j0 = p >> 2;                  // granule index
  const int ob = (p & 3) << 2;            // byte offset within granule
  // pass A: rows 32*ge + r  (two sweeps)
#pragma unroll
  for (int swp = 0; swp < 2; ++swp) {
    const int ge = (tid >> 5) + (swp << 4);
    float va[32], vb[32];
#pragma unroll
    for (int r = 0; r < 32; ++r) {
      int row = (ge << 5) + r;
      ushort2 u = *(const ushort2*)(tb + (row << 7) + ((j0 ^ (row & 7)) << 4) + ob);
      va[r] = bf2f(u.x); vb[r] = bf2f(u.y);
    }
    wht_inreg<32>(va); wht_inreg<32>(vb);
#pragma unroll
    for (int r = 0; r < 32; ++r) {
      int row = (ge << 5) + r;
      ushort2 u; u.x = f2bf(va[r]); u.y = f2bf(vb[r]);
      *(ushort2*)(tb + (row << 7) + ((j0 ^ (row & 7)) << 4) + ob) = u;
    }
  }
  __syncthreads();
  // pass B: rows ge + 32*r
#pragma unroll
  for (int swp = 0; swp < 2; ++swp) {
    const int ge = (tid >> 5) + (swp << 4);
    float va[32], vb[32];
#pragma unroll
    for (int r = 0; r < 32; ++r) {
      int row = ge + (r << 5);
      ushort2 u = *(const ushort2*)(tb + (row << 7) + ((j0 ^ (row & 7)) << 4) + ob);
      va[r] = bf2f(u.x); vb[r] = bf2f(u.y);
    }
    wht_inreg<32>(va); wht_inreg<32>(vb);
#pragma unroll
    for (int r = 0; r < 32; ++r) {
      int row = ge + (r << 5);
      ushort2 u; u.x = f2bf(va[r]); u.y = f2bf(vb[r]);
      *(ushort2*)(tb + (row << 7) + ((j0 ^ (row & 7)) << 4) + ob) = u;
    }
  }
  __syncthreads();
  // epilogue: W = W0 + m5*sc -> bf16 (full-line r/w)
#pragma unroll
  for (int h = 0; h < 2; ++h) {
    int r = tid + (h << 9);
    size_t gb = ((size_t)r << 13) + cb;
#pragma unroll
    for (int j = 0; j < 8; ++j) {
      short8 d = *(const short8*)(tb + (r << 7) + ((j ^ (r & 7)) << 4));
      float4 w0a = *(const float4*)(W0 + gb + (j << 3));
      float4 w0b = *(const float4*)(W0 + gb + (j << 3) + 4);
      short8 o;
      o[0] = (short)f2bf(bf2f((ushort)d[0]) * sc + w0a.x);
      o[1] = (short)f2bf(bf2f((ushort)d[1]) * sc + w0a.y);
      o[2] = (short)f2bf(bf2f((ushort)d[2]) * sc + w0a.z);
      o[3] = (short)f2bf(bf2f((ushort)d[3]) * sc + w0a.w);
      o[4] = (short)f2bf(bf2f((ushort)d[4]) * sc + w0b.x);
      o[5] = (short)f2bf(bf2f((ushort)d[5]) * sc + w0b.y);
      o[6] = (short)f2bf(bf2f((ushort)d[6]) * sc + w0b.z);
      o[7] = (short)f2bf(bf2f((ushort)d[7]) * sc + w0b.w);
      *(short8*)(Wb + gb + (j << 3)) = o;
    }
  }
}

// ---------------- gemm_sp: C-partial = A*B^T over K-slice blockIdx.z.
// 128x128 tile, BK=64, 4 waves (2x2), 2-buffer LDS (64 KB -> 2 blocks/CU:
// the co-resident block's MFMAs cover this block's vm0/barrier stalls).
// STAGE after barrier (WAR-safe: buf[(t+1)&1] was fully read in iter t-1).
// Output: bf16 partial plane P[z].
template <int NT>
__global__ __launch_bounds__(256) void gemm_sp(
    const ushort* __restrict__ A, const ushort* __restrict__ B,
    ushort* __restrict__ P0, ushort* __restrict__ P1,
    ushort* __restrict__ P2, ushort* __restrict__ P3,
    int M, int N, int K) {
  __shared__ ushort As[2][8192];
  __shared__ ushort Bs[2][8192];
  const int tid = threadIdx.x;
  const int w = tid >> 6, l = tid & 63;
  const int wr = w >> 1, wc = w & 1;
  const int brow = blockIdx.y << 7, bcol = blockIdx.x << 7;
  const int lrow = l >> 3;                       // row within 8-row chunk
  const int csrc = ((l & 7) ^ lrow) << 3;        // swizzled source col (ushort)
  const int l15 = l & 15;
  const int x7 = l15 & 7;
  const int z = blockIdx.z;
  const int kb = z * (NT << 6);
  ushort* __restrict__ P = z == 0 ? P0 : z == 1 ? P1 : z == 2 ? P2 : P3;
  f32x4 acc[4][4] = {};

  const ushort* pa = A + (size_t)(brow + (w << 5) + lrow) * K + kb + csrc;
  const ushort* pb = B + (size_t)(bcol + (w << 5) + lrow) * K + kb + csrc;
  const size_t K8 = (size_t)K << 3;

#define STAGE(buf, tt)                                                      \
  {                                                                         \
    const ushort* qa = pa + ((tt) << 6);                                    \
    const ushort* qb = pb + ((tt) << 6);                                    \
    _Pragma("unroll")                                                       \
    for (int i = 0; i < 4; ++i) {                                           \
      gload_lds16(qa + K8 * i, &As[buf][(((w << 2) + i) << 9)]);            \
      gload_lds16(qb + K8 * i, &Bs[buf][(((w << 2) + i) << 9)]);            \
    }                                                                       \
  }

  STAGE(0, 0);
  for (int t = 0; t < NT; ++t) {
    wait_vm0();                               // tile t landed
    barrier_raw();                            // all waves done reading buf[(t+1)&1]
    if (t + 1 < NT) STAGE((t + 1) & 1, t + 1);
    const ushort* Acur = As[t & 1];
    const ushort* Bcur = Bs[t & 1];
    bf16x8 af[2][4], bfr[2][4];
#pragma unroll
    for (int kk = 0; kk < 2; ++kk) {
      int c8 = (kk << 2) + (l >> 4);
#pragma unroll
      for (int m = 0; m < 4; ++m)
        af[kk][m] = *(const bf16x8*)&Acur[(((wr << 6) + (m << 4) + l15) << 6) + ((c8 ^ x7) << 3)];
#pragma unroll
      for (int n = 0; n < 4; ++n)
        bfr[kk][n] = *(const bf16x8*)&Bcur[(((wc << 6) + (n << 4) + l15) << 6) + ((c8 ^ x7) << 3)];
    }
    wait_lgkm0();
#pragma unroll
    for (int kk = 0; kk < 2; ++kk)
#pragma unroll
      for (int m = 0; m < 4; ++m)
#pragma unroll
        for (int n = 0; n < 4; ++n)
          acc[m][n] = __builtin_amdgcn_mfma_f32_16x16x32_bf16(af[kk][m], bfr[kk][n], acc[m][n], 0, 0, 0);
  }
#undef STAGE

#pragma unroll
  for (int n = 0; n < 4; ++n) {
    int col = bcol + (wc << 6) + (n << 4) + l15;
#pragma unroll
    for (int m = 0; m < 4; ++m) {
      int row0 = brow + (wr << 6) + (m << 4) + ((l >> 4) << 2);
#pragma unroll
      for (int j = 0; j < 4; ++j)
        P[(size_t)(row0 + j) * N + col] = f2bf(acc[m][n][j]);
    }
  }
}

// ---------------- h = relu(G0 + G1 + b1)  (1024x4096, bf16 planes -> bf16)
__global__ __launch_bounds__(256) void hfuse(
    const ushort4* __restrict__ G0, const ushort4* __restrict__ G1,
    const float* __restrict__ b1, ushort4* __restrict__ hb) {
  int i = blockIdx.x * 256 + threadIdx.x;       // 1048576 u4
  ushort4 a = G0[i], b = G1[i];
  const float4 bv = *(const float4*)(b1 + ((i & 1023) << 2));
  ushort4 o;
  o.x = f2bf(fmaxf(bf2f(a.x) + bf2f(b.x) + bv.x, 0.f));
  o.y = f2bf(fmaxf(bf2f(a.y) + bf2f(b.y) + bv.y, 0.f));
  o.z = f2bf(fmaxf(bf2f(a.z) + bf2f(b.z) + bv.z, 0.f));
  o.w = f2bf(fmaxf(bf2f(a.w) + bf2f(b.w) + bv.w, 0.f));
  hb[i] = o;
}

// ---------------- out = Q0+Q1+Q2+Q3 + b2   (1024x2048, bf16 planes -> f32)
__global__ __launch_bounds__(256) void reduce_out4(
    const ushort4* __restrict__ Q0, const ushort4* __restrict__ Q1,
    const ushort4* __restrict__ Q2, const ushort4* __restrict__ Q3,
    const float* __restrict__ b2, float4* __restrict__ out) {
  int i = blockIdx.x * 256 + threadIdx.x;       // 524288 u4
  ushort4 a = Q0[i], b = Q1[i], c = Q2[i], d = Q3[i];
  const float4 bb = *(const float4*)(b2 + ((i & 511) << 2));
  float4 o;
  o.x = bf2f(a.x) + bf2f(b.x) + bf2f(c.x) + bf2f(d.x) + bb.x;
  o.y = bf2f(a.y) + bf2f(b.y) + bf2f(c.y) + bf2f(d.y) + bb.y;
  o.z = bf2f(a.z) + bf2f(b.z) + bf2f(c.z) + bf2f(d.z) + bb.z;
  o.w = bf2f(a.w) + bf2f(b.w) + bf2f(c.w) + bf2f(d.w) + bb.w;
  out[i] = o;
}

extern "C" void kernel_launch(void* const* d_in, const int* in_sizes, int n_in,
                              void* d_out, int out_size, void* d_ws, size_t ws_size,
                              hipStream_t stream) {
  const float* x     = (const float*)d_in[0];
  const float* V     = (const float*)d_in[1];
  const float* W1_0  = (const float*)d_in[2];
  const float* b1_0  = (const float*)d_in[3];
  const float* W2_0  = (const float*)d_in[4];
  const float* b2_0  = (const float*)d_in[5];
  const float* BB_W1 = (const float*)d_in[6];
  const int*   Pi_W1 = (const int*)d_in[7];
  const float* GG_W1 = (const float*)d_in[8];
  const float* BB_b1 = (const float*)d_in[9];
  const int*   Pi_b1 = (const int*)d_in[10];
  const float* GG_b1 = (const float*)d_in[11];
  const float* BB_W2 = (const float*)d_in[12];
  const int*   Pi_W2 = (const int*)d_in[13];
  const float* GG_W2 = (const float*)d_in[14];
  const float* BB_b2 = (const float*)d_in[15];
  const int*   Pi_b2 = (const int*)d_in[16];
  const float* GG_b2 = (const float*)d_in[17];
  float* out = (float*)d_out;

  const size_t MB = 1048576ull;
  char* ws = (char*)d_ws;
  // inter1@0 / inter2@16 die after ff_pass2; G planes (gemm1, 8MB each) alias
  // inter1; Q planes (gemm2, 4MB each) alias inter2.
  ushort* inter1 = (ushort*)(ws);
  ushort* G0     = (ushort*)(ws);
  ushort* G1     = (ushort*)(ws + 8 * MB);
  ushort* inter2 = (ushort*)(ws + 16 * MB);
  ushort* Q0     = (ushort*)(ws + 16 * MB);
  ushort* Q1     = (ushort*)(ws + 20 * MB);
  ushort* Q2     = (ushort*)(ws + 24 * MB);
  ushort* Q3     = (ushort*)(ws + 28 * MB);
  ushort* W1b    = (ushort*)(ws + 32 * MB);
  ushort* W2b    = (ushort*)(ws + 48 * MB);
  ushort* xb     = (ushort*)(ws + 64 * MB);
  ushort* hb     = (ushort*)(ws + 68 * MB);
  char*   S      = ws + 76 * MB;
  float*  t1     = (float*)(S);
  float*  t2     = (float*)(S + 4096);
  float*  b1     = (float*)(S + 8192);
  float*  b2     = (float*)(S + 8192 + 16384);
  float*  parts  = (float*)(S + 8192 + 16384 + 8192);   // 2048 floats

  prep<<<2052, 256, 0, stream>>>((const float4*)x, (ushort4*)xb, V,
                                 BB_W1, BB_W2, t1, t2,
                                 BB_b1, Pi_b1, GG_b1, b1_0,
                                 BB_b2, Pi_b2, GG_b2, b2_0, b1, b2);

  ff_pass1<<<2048, 256, 0, stream>>>(Pi_W1, GG_W1, Pi_W2, GG_W2, t1, t2,
                                     inter1, inter2, parts);
  ff_pass2<<<256, 512, 0, stream>>>(inter1, inter2, W1_0, W2_0, parts, W1b, W2b);

  // gemm1: x @ W1b^T, K=2048 split-K2 -> G0,G1 (512 blocks, 2/CU)
  gemm_sp<16><<<dim3(32, 8, 2), 256, 0, stream>>>(xb, W1b, G0, G1, nullptr, nullptr,
                                                  1024, 4096, 2048);
  // h = relu(G0+G1+b1)
  hfuse<<<4096, 256, 0, stream>>>((const ushort4*)G0, (const ushort4*)G1, b1,
                                  (ushort4*)hb);
  // gemm2: h @ W2b^T, K=4096 split-K4 -> Q0..Q3 (512 blocks, 2/CU)
  gemm_sp<16><<<dim3(16, 8, 4), 256, 0, stream>>>(hb, W2b, Q0, Q1, Q2, Q3,
                                                  1024, 2048, 4096);
  // out = Q0+Q1+Q2+Q3 + b2
  reduce_out4<<<2048, 256, 0, stream>>>((const ushort4*)Q0, (const ushort4*)Q1,
                                        (const ushort4*)Q2, (const ushort4*)Q3,
                                        b2, (float4*)out);
}

// Round 13
// 155.513 us; speedup vs baseline: 1.6129x; 1.0134x over previous
//
#include <hip/hip_runtime.h>
#include <hip/hip_bf16.h>
#include <stdint.h>

// B=1024, D_IN=2048, D_H=4096, D_OUT=2048, D_INT=1024
// r12 skeleton (best: 157.6us) + ff_pass2 W0-register-prefetch across
// lgkm-only barriers (T14: hide the 64MB W0 stream under the WHT phases).

typedef __attribute__((ext_vector_type(8))) short bf16x8;   // 8 bf16 (4 VGPRs)
typedef __attribute__((ext_vector_type(8))) short short8;
typedef __attribute__((ext_vector_type(4))) float f32x4;

__device__ __forceinline__ ushort f2bf(float f) {           // RNE f32->bf16
  union { float f; uint32_t u; } v; v.f = f;
  return (ushort)((v.u + 0x7FFFu + ((v.u >> 16) & 1u)) >> 16);
}
__device__ __forceinline__ float bf2f(ushort u) {
  union { uint32_t u; float f; } v; v.u = (uint32_t)u << 16; return v.f;
}

__device__ __forceinline__ void gload_lds16(const void* g, void* l) {
  __builtin_amdgcn_global_load_lds(
      (const __attribute__((address_space(1))) void*)g,
      (__attribute__((address_space(3))) void*)l, 16, 0, 0);
}

__device__ __forceinline__ void wait_vm0()  { asm volatile("s_waitcnt vmcnt(0)"  ::: "memory"); }
__device__ __forceinline__ void wait_lgkm0(){ asm volatile("s_waitcnt lgkmcnt(0)" ::: "memory"); }
__device__ __forceinline__ void barrier_raw(){ asm volatile("s_barrier" ::: "memory"); }
// barrier that does NOT drain vmcnt (keeps global prefetch loads in flight)
__device__ __forceinline__ void lds_barrier() {
  wait_lgkm0();
  barrier_raw();
  __builtin_amdgcn_sched_barrier(0);
}

template <int NN>
__device__ __forceinline__ void wht_inreg(float* v) {
#pragma unroll
  for (int h = 1; h < NN; h <<= 1)
#pragma unroll
    for (int g = 0; g < NN; g += (h << 1))
#pragma unroll
      for (int k = 0; k < h; ++k) {
        float a = v[g + k], b = v[g + k + h];
        v[g + k] = a + b; v[g + k + h] = a - b;
      }
}

// ---------------- prep: fused  (a) x f32->bf16 cvt [blocks 0..2047]
//                               (b) t = WHT_1024(BB*V) for W1/W2 [2048..2049]
//                               (c) full bias fastfood b1/b2 [2050..2051]
__global__ __launch_bounds__(256) void prep(
    const float4* __restrict__ x4, ushort4* __restrict__ xb4,
    const float* __restrict__ V,
    const float* __restrict__ BBW1, const float* __restrict__ BBW2,
    float* __restrict__ t1, float* __restrict__ t2,
    const float* __restrict__ BBb1, const int* __restrict__ Pib1,
    const float* __restrict__ GGb1, const float* __restrict__ b10,
    const float* __restrict__ BBb2, const int* __restrict__ Pib2,
    const float* __restrict__ GGb2, const float* __restrict__ b20,
    float* __restrict__ ob1, float* __restrict__ ob2) {
  __shared__ float ts[1024];
  __shared__ float zs[4096];
  __shared__ float red[4];
  const int bid = blockIdx.x;
  const int tid = threadIdx.x;

  if (bid < 2048) {                       // role (a): cvt
    int i = bid * 256 + tid;
    float4 v = x4[i];
    ushort4 o;
    o.x = f2bf(v.x); o.y = f2bf(v.y); o.z = f2bf(v.z); o.w = f2bf(v.w);
    xb4[i] = o;
    return;
  }

  if (bid < 2050) {                       // role (b): make_t
    const int which = bid - 2048;
    const float* BB = which ? BBW2 : BBW1;
    float* t = which ? t2 : t1;
    for (int i = tid; i < 1024; i += 256) ts[i] = BB[i] * V[i];
    for (int st = 0; st < 10; ++st) {
      int half = 1 << st;
      __syncthreads();
      for (int j = tid; j < 512; j += 256) {
        int p = ((j >> st) << (st + 1)) | (j & (half - 1));
        float a = ts[p], b = ts[p + half];
        ts[p] = a + b; ts[p + half] = a - b;
      }
    }
    __syncthreads();
    for (int i = tid; i < 1024; i += 256) t[i] = ts[i];
    return;
  }

  // role (c): bias fastfood
  {
    const int which = bid - 2050;
    const int L = which ? 2048 : 4096;
    const float* BB = which ? BBb2 : BBb1;
    const int* Pi = which ? Pib2 : Pib1;
    const float* GG = which ? GGb2 : GGb1;
    const float* b0 = which ? b20 : b10;
    float* ob = which ? ob2 : ob1;

    for (int i = tid; i < 1024; i += 256) ts[i] = BB[i] * V[i];
    for (int st = 0; st < 10; ++st) {
      int half = 1 << st;
      __syncthreads();
      for (int j = tid; j < 512; j += 256) {
        int p = ((j >> st) << (st + 1)) | (j & (half - 1));
        float a = ts[p], b = ts[p + half];
        ts[p] = a + b; ts[p + half] = a - b;
      }
    }
    __syncthreads();
    float gsum = 0.f;
    for (int i = tid; i < L; i += 256) {
      int pi = Pi[i];
      float g = GG[i];
      gsum += g * g;
      zs[i] = ts[pi & 1023] * g;
    }
    for (int o = 32; o > 0; o >>= 1) gsum += __shfl_down(gsum, o);
    if ((tid & 63) == 0) red[tid >> 6] = gsum;
    __syncthreads();
    float ssum = red[0] + red[1] + red[2] + red[3];
    for (int st = 0; (1 << st) < L; ++st) {
      int half = 1 << st;
      __syncthreads();
      for (int j = tid; j < (L >> 1); j += 256) {
        int p = ((j >> st) << (st + 1)) | (j & (half - 1));
        float a = zs[p], b = zs[p + half];
        zs[p] = a + b; zs[p + half] = a - b;
      }
    }
    __syncthreads();
    float scale = rsqrtf((float)L * ssum);
    for (int i = tid; i < L; i += 256) ob[i] = b0[i] + zs[i] * scale;
  }
}

// ---------------- pass 1 (both weights): z = t[Pi&1023]*GG, WHT_8192 on
// contiguous 8192-chunks (bits 0..12) via radix 32(b3-7)/32(b8-12)/8(b0-2)
// register passes; skewed f32 LDS slot = i + (i>>5) keeps all phases <=2-way.
// [r3/r8/r12-proven; sits at the gather-stream floor (~53us, 7 variants)]
__global__ __launch_bounds__(256) void ff_pass1(
    const int* __restrict__ Pi1, const float* __restrict__ GG1,
    const int* __restrict__ Pi2, const float* __restrict__ GG2,
    const float* __restrict__ t1, const float* __restrict__ t2,
    ushort* __restrict__ inter1, ushort* __restrict__ inter2,
    float* __restrict__ partials) {
  __shared__ float ts[1024];
  __shared__ float zs[8448];        // 8192 + skew
  __shared__ float red[4];
  int tid = threadIdx.x;
  int wsel = blockIdx.x >> 10;
  int blk = blockIdx.x & 1023;
  const int* Pi = wsel ? Pi2 : Pi1;
  const float* GG = wsel ? GG2 : GG1;
  const float* t = wsel ? t2 : t1;
  ushort* inter = wsel ? inter2 : inter1;
  size_t base = (size_t)blk * 8192;

  for (int i = tid; i < 1024; i += 256) ts[i] = t[i];
  __syncthreads();

  const int4* Pi4 = (const int4*)(Pi + base);
  const float4* GG4 = (const float4*)(GG + base);
  float gsum = 0.f;
#pragma unroll
  for (int q = 0; q < 8; ++q) {
    int u = (q << 8) + tid;          // 0..2047
    int4 p4 = Pi4[u];
    float4 g4 = GG4[u];
    gsum += g4.x * g4.x + g4.y * g4.y + g4.z * g4.z + g4.w * g4.w;
    int i0 = u << 2;
    float4 z;
    z.x = ts[p4.x & 1023] * g4.x;
    z.y = ts[p4.y & 1023] * g4.y;
    z.z = ts[p4.z & 1023] * g4.z;
    z.w = ts[p4.w & 1023] * g4.w;
    *(float4*)&zs[i0 + (i0 >> 5)] = z;
  }
  for (int o = 32; o > 0; o >>= 1) gsum += __shfl_down(gsum, o);
  if ((tid & 63) == 0) red[tid >> 6] = gsum;
  __syncthreads();
  if (tid == 0) partials[blockIdx.x] = red[0] + red[1] + red[2] + red[3];

  float v[32];
  // pass A: bits 3-7
  {
    int o = (tid & 7) | ((tid >> 3) << 8);
#pragma unroll
    for (int r = 0; r < 32; ++r) { int i = o + (r << 3); v[r] = zs[i + (i >> 5)]; }
    wht_inreg<32>(v);
#pragma unroll
    for (int r = 0; r < 32; ++r) { int i = o + (r << 3); zs[i + (i >> 5)] = v[r]; }
  }
  __syncthreads();
  // pass B: bits 8-12
  {
#pragma unroll
    for (int r = 0; r < 32; ++r) { int i = tid | (r << 8); v[r] = zs[i + (i >> 5)]; }
    wht_inreg<32>(v);
#pragma unroll
    for (int r = 0; r < 32; ++r) { int i = tid | (r << 8); zs[i + (i >> 5)] = v[r]; }
  }
  __syncthreads();
  // pass C: bits 0-2 (4 runs of 8) + coalesced short8 stores
  {
    int tp = ((tid & 63) << 3) | ((tid >> 6) << 11);
#pragma unroll
    for (int j = 0; j < 4; ++j)
#pragma unroll
      for (int k = 0; k < 8; ++k) { int i = tp + (j << 9) + k; v[(j << 3) + k] = zs[i + (i >> 5)]; }
#pragma unroll
    for (int j = 0; j < 4; ++j) wht_inreg<8>(v + (j << 3));
#pragma unroll
    for (int j = 0; j < 4; ++j) {
      short8 s;
#pragma unroll
      for (int k = 0; k < 8; ++k) s[k] = (short)f2bf(v[(j << 3) + k]);
      *(short8*)(inter + base + tp + (j << 9)) = s;
    }
  }
}

// ---------------- pass 2 (both weights): WHT_1024 over h (global bits 13..22,
// stride 8192) on a [1024 rows x 64 cols] bf16 LDS tile. NEW vs r12: the W0
// stream (64MB f32, half this kernel's traffic) is register-prefetched —
// h=0 batch issued after phase-1's ds_writes (in flight across passA+passB),
// h=1 batch issued after passB — and all intra-kernel barriers are lgkm-only
// (raw s_barrier), so the prefetch is never drained. Peak VGPR ~190, no spill.
__global__ __launch_bounds__(512) void ff_pass2(
    const ushort* __restrict__ inter1, const ushort* __restrict__ inter2,
    const float* __restrict__ W01, const float* __restrict__ W02,
    const float* __restrict__ partials,
    ushort* __restrict__ W1b, ushort* __restrict__ W2b) {
  __shared__ ushort tile[65536];          // 128 KB
  __shared__ float red[8];
  const int tid = threadIdx.x;
  const int wsel = blockIdx.x >> 7;
  const int cb = (blockIdx.x & 127) << 6;
  const ushort* __restrict__ inter = wsel ? inter2 : inter1;
  const float* __restrict__ W0 = wsel ? W02 : W01;
  ushort* __restrict__ Wb = wsel ? W2b : W1b;
  char* tb = (char*)tile;

  float s = partials[(wsel << 10) + tid] + partials[(wsel << 10) + tid + 512];
  for (int o = 32; o > 0; o >>= 1) s += __shfl_down(s, o);
  if ((tid & 63) == 0) red[tid >> 6] = s;

  // phase 1: coalesced row loads (128 B/lane/row), swizzled LDS stores
#pragma unroll
  for (int h = 0; h < 2; ++h) {
    int r = tid + (h << 9);
    const ushort* gp = inter + ((size_t)r << 13) + cb;
#pragma unroll
    for (int j = 0; j < 8; ++j) {
      short8 d = *(const short8*)(gp + (j << 3));
      *(short8*)(tb + (r << 7) + ((j ^ (r & 7)) << 4)) = d;
    }
  }
  // W0 prefetch, h=0 rows: stays in flight across passA + passB
  float4 w0a0[8], w0b0[8];
  {
    const size_t gb = ((size_t)tid << 13) + cb;
#pragma unroll
    for (int j = 0; j < 8; ++j) {
      w0a0[j] = *(const float4*)(W0 + gb + (j << 3));
      w0b0[j] = *(const float4*)(W0 + gb + (j << 3) + 4);
    }
  }
  lds_barrier();                          // lgkm only: W0 loads NOT drained
  float ssum = 0.f;
#pragma unroll
  for (int k = 0; k < 8; ++k) ssum += red[k];
  const float sc = rsqrtf(8388608.f * ssum);

  const int p = tid & 31;                 // col pair 2p
  const int j0 = p >> 2;                  // granule index
  const int ob = (p & 3) << 2;            // byte offset within granule
  // pass A: rows 32*ge + r  (two sweeps)
#pragma unroll
  for (int swp = 0; swp < 2; ++swp) {
    const int ge = (tid >> 5) + (swp << 4);
    float va[32], vb[32];
#pragma unroll
    for (int r = 0; r < 32; ++r) {
      int row = (ge << 5) + r;
      ushort2 u = *(const ushort2*)(tb + (row << 7) + ((j0 ^ (row & 7)) << 4) + ob);
      va[r] = bf2f(u.x); vb[r] = bf2f(u.y);
    }
    wht_inreg<32>(va); wht_inreg<32>(vb);
#pragma unroll
    for (int r = 0; r < 32; ++r) {
      int row = (ge << 5) + r;
      ushort2 u; u.x = f2bf(va[r]); u.y = f2bf(vb[r]);
      *(ushort2*)(tb + (row << 7) + ((j0 ^ (row & 7)) << 4) + ob) = u;
    }
  }
  lds_barrier();
  // pass B: rows ge + 32*r
#pragma unroll
  for (int swp = 0; swp < 2; ++swp) {
    const int ge = (tid >> 5) + (swp << 4);
    float va[32], vb[32];
#pragma unroll
    for (int r = 0; r < 32; ++r) {
      int row = ge + (r << 5);
      ushort2 u = *(const ushort2*)(tb + (row << 7) + ((j0 ^ (row & 7)) << 4) + ob);
      va[r] = bf2f(u.x); vb[r] = bf2f(u.y);
    }
    wht_inreg<32>(va); wht_inreg<32>(vb);
#pragma unroll
    for (int r = 0; r < 32; ++r) {
      int row = ge + (r << 5);
      ushort2 u; u.x = f2bf(va[r]); u.y = f2bf(vb[r]);
      *(ushort2*)(tb + (row << 7) + ((j0 ^ (row & 7)) << 4) + ob) = u;
    }
  }
  // W0 prefetch, h=1 rows: in flight across the barrier + epilogue h=0
  float4 w0a1[8], w0b1[8];
  {
    const size_t gb = ((size_t)(tid + 512) << 13) + cb;
#pragma unroll
    for (int j = 0; j < 8; ++j) {
      w0a1[j] = *(const float4*)(W0 + gb + (j << 3));
      w0b1[j] = *(const float4*)(W0 + gb + (j << 3) + 4);
    }
  }
  lds_barrier();
  // epilogue: W = W0 + m5*sc -> bf16 (full-line writes), W0 from registers
  {
    const int r = tid;
    const size_t gb = ((size_t)r << 13) + cb;
#pragma unroll
    for (int j = 0; j < 8; ++j) {
      short8 d = *(const short8*)(tb + (r << 7) + ((j ^ (r & 7)) << 4));
      short8 o;
      o[0] = (short)f2bf(bf2f((ushort)d[0]) * sc + w0a0[j].x);
      o[1] = (short)f2bf(bf2f((ushort)d[1]) * sc + w0a0[j].y);
      o[2] = (short)f2bf(bf2f((ushort)d[2]) * sc + w0a0[j].z);
      o[3] = (short)f2bf(bf2f((ushort)d[3]) * sc + w0a0[j].w);
      o[4] = (short)f2bf(bf2f((ushort)d[4]) * sc + w0b0[j].x);
      o[5] = (short)f2bf(bf2f((ushort)d[5]) * sc + w0b0[j].y);
      o[6] = (short)f2bf(bf2f((ushort)d[6]) * sc + w0b0[j].z);
      o[7] = (short)f2bf(bf2f((ushort)d[7]) * sc + w0b0[j].w);
      *(short8*)(Wb + gb + (j << 3)) = o;
    }
  }
  {
    const int r = tid + 512;
    const size_t gb = ((size_t)r << 13) + cb;
#pragma unroll
    for (int j = 0; j < 8; ++j) {
      short8 d = *(const short8*)(tb + (r << 7) + ((j ^ (r & 7)) << 4));
      short8 o;
      o[0] = (short)f2bf(bf2f((ushort)d[0]) * sc + w0a1[j].x);
      o[1] = (short)f2bf(bf2f((ushort)d[1]) * sc + w0a1[j].y);
      o[2] = (short)f2bf(bf2f((ushort)d[2]) * sc + w0a1[j].z);
      o[3] = (short)f2bf(bf2f((ushort)d[3]) * sc + w0a1[j].w);
      o[4] = (short)f2bf(bf2f((ushort)d[4]) * sc + w0b1[j].x);
      o[5] = (short)f2bf(bf2f((ushort)d[5]) * sc + w0b1[j].y);
      o[6] = (short)f2bf(bf2f((ushort)d[6]) * sc + w0b1[j].z);
      o[7] = (short)f2bf(bf2f((ushort)d[7]) * sc + w0b1[j].w);
      *(short8*)(Wb + gb + (j << 3)) = o;
    }
  }
}

// ---------------- gemm_sp: C-partial = A*B^T over K-slice blockIdx.z.
// 128x128 tile, BK=64, 4 waves (2x2), 2-buffer LDS (64 KB -> 2 blocks/CU:
// the co-resident block's MFMAs cover this block's vm0/barrier stalls).
// [r12-proven: took total 171->157.6]
template <int NT>
__global__ __launch_bounds__(256) void gemm_sp(
    const ushort* __restrict__ A, const ushort* __restrict__ B,
    ushort* __restrict__ P0, ushort* __restrict__ P1,
    ushort* __restrict__ P2, ushort* __restrict__ P3,
    int M, int N, int K) {
  __shared__ ushort As[2][8192];
  __shared__ ushort Bs[2][8192];
  const int tid = threadIdx.x;
  const int w = tid >> 6, l = tid & 63;
  const int wr = w >> 1, wc = w & 1;
  const int brow = blockIdx.y << 7, bcol = blockIdx.x << 7;
  const int lrow = l >> 3;                       // row within 8-row chunk
  const int csrc = ((l & 7) ^ lrow) << 3;        // swizzled source col (ushort)
  const int l15 = l & 15;
  const int x7 = l15 & 7;
  const int z = blockIdx.z;
  const int kb = z * (NT << 6);
  ushort* __restrict__ P = z == 0 ? P0 : z == 1 ? P1 : z == 2 ? P2 : P3;
  f32x4 acc[4][4] = {};

  const ushort* pa = A + (size_t)(brow + (w << 5) + lrow) * K + kb + csrc;
  const ushort* pb = B + (size_t)(bcol + (w << 5) + lrow) * K + kb + csrc;
  const size_t K8 = (size_t)K << 3;

#define STAGE(buf, tt)                                                      \
  {                                                                         \
    const ushort* qa = pa + ((tt) << 6);                                    \
    const ushort* qb = pb + ((tt) << 6);                                    \
    _Pragma("unroll")                                                       \
    for (int i = 0; i < 4; ++i) {                                           \
      gload_lds16(qa + K8 * i, &As[buf][(((w << 2) + i) << 9)]);            \
      gload_lds16(qb + K8 * i, &Bs[buf][(((w << 2) + i) << 9)]);            \
    }                                                                       \
  }

  STAGE(0, 0);
  for (int t = 0; t < NT; ++t) {
    wait_vm0();                               // tile t landed
    barrier_raw();                            // all waves done reading buf[(t+1)&1]
    if (t + 1 < NT) STAGE((t + 1) & 1, t + 1);
    const ushort* Acur = As[t & 1];
    const ushort* Bcur = Bs[t & 1];
    bf16x8 af[2][4], bfr[2][4];
#pragma unroll
    for (int kk = 0; kk < 2; ++kk) {
      int c8 = (kk << 2) + (l >> 4);
#pragma unroll
      for (int m = 0; m < 4; ++m)
        af[kk][m] = *(const bf16x8*)&Acur[(((wr << 6) + (m << 4) + l15) << 6) + ((c8 ^ x7) << 3)];
#pragma unroll
      for (int n = 0; n < 4; ++n)
        bfr[kk][n] = *(const bf16x8*)&Bcur[(((wc << 6) + (n << 4) + l15) << 6) + ((c8 ^ x7) << 3)];
    }
    wait_lgkm0();
#pragma unroll
    for (int kk = 0; kk < 2; ++kk)
#pragma unroll
      for (int m = 0; m < 4; ++m)
#pragma unroll
        for (int n = 0; n < 4; ++n)
          acc[m][n] = __builtin_amdgcn_mfma_f32_16x16x32_bf16(af[kk][m], bfr[kk][n], acc[m][n], 0, 0, 0);
  }
#undef STAGE

#pragma unroll
  for (int n = 0; n < 4; ++n) {
    int col = bcol + (wc << 6) + (n << 4) + l15;
#pragma unroll
    for (int m = 0; m < 4; ++m) {
      int row0 = brow + (wr << 6) + (m << 4) + ((l >> 4) << 2);
#pragma unroll
      for (int j = 0; j < 4; ++j)
        P[(size_t)(row0 + j) * N + col] = f2bf(acc[m][n][j]);
    }
  }
}

// ---------------- h = relu(G0 + G1 + b1)  (1024x4096, bf16 planes -> bf16)
__global__ __launch_bounds__(256) void hfuse(
    const ushort4* __restrict__ G0, const ushort4* __restrict__ G1,
    const float* __restrict__ b1, ushort4* __restrict__ hb) {
  int i = blockIdx.x * 256 + threadIdx.x;       // 1048576 u4
  ushort4 a = G0[i], b = G1[i];
  const float4 bv = *(const float4*)(b1 + ((i & 1023) << 2));
  ushort4 o;
  o.x = f2bf(fmaxf(bf2f(a.x) + bf2f(b.x) + bv.x, 0.f));
  o.y = f2bf(fmaxf(bf2f(a.y) + bf2f(b.y) + bv.y, 0.f));
  o.z = f2bf(fmaxf(bf2f(a.z) + bf2f(b.z) + bv.z, 0.f));
  o.w = f2bf(fmaxf(bf2f(a.w) + bf2f(b.w) + bv.w, 0.f));
  hb[i] = o;
}

// ---------------- out = Q0+Q1+Q2+Q3 + b2   (1024x2048, bf16 planes -> f32)
__global__ __launch_bounds__(256) void reduce_out4(
    const ushort4* __restrict__ Q0, const ushort4* __restrict__ Q1,
    const ushort4* __restrict__ Q2, const ushort4* __restrict__ Q3,
    const float* __restrict__ b2, float4* __restrict__ out) {
  int i = blockIdx.x * 256 + threadIdx.x;       // 524288 u4
  ushort4 a = Q0[i], b = Q1[i], c = Q2[i], d = Q3[i];
  const float4 bb = *(const float4*)(b2 + ((i & 511) << 2));
  float4 o;
  o.x = bf2f(a.x) + bf2f(b.x) + bf2f(c.x) + bf2f(d.x) + bb.x;
  o.y = bf2f(a.y) + bf2f(b.y) + bf2f(c.y) + bf2f(d.y) + bb.y;
  o.z = bf2f(a.z) + bf2f(b.z) + bf2f(c.z) + bf2f(d.z) + bb.z;
  o.w = bf2f(a.w) + bf2f(b.w) + bf2f(c.w) + bf2f(d.w) + bb.w;
  out[i] = o;
}

extern "C" void kernel_launch(void* const* d_in, const int* in_sizes, int n_in,
                              void* d_out, int out_size, void* d_ws, size_t ws_size,
                              hipStream_t stream) {
  const float* x     = (const float*)d_in[0];
  const float* V     = (const float*)d_in[1];
  const float* W1_0  = (const float*)d_in[2];
  const float* b1_0  = (const float*)d_in[3];
  const float* W2_0  = (const float*)d_in[4];
  const float* b2_0  = (const float*)d_in[5];
  const float* BB_W1 = (const float*)d_in[6];
  const int*   Pi_W1 = (const int*)d_in[7];
  const float* GG_W1 = (const float*)d_in[8];
  const float* BB_b1 = (const float*)d_in[9];
  const int*   Pi_b1 = (const int*)d_in[10];
  const float* GG_b1 = (const float*)d_in[11];
  const float* BB_W2 = (const float*)d_in[12];
  const int*   Pi_W2 = (const int*)d_in[13];
  const float* GG_W2 = (const float*)d_in[14];
  const float* BB_b2 = (const float*)d_in[15];
  const int*   Pi_b2 = (const int*)d_in[16];
  const float* GG_b2 = (const float*)d_in[17];
  float* out = (float*)d_out;

  const size_t MB = 1048576ull;
  char* ws = (char*)d_ws;
  // inter1@0 / inter2@16 die after ff_pass2; G planes (gemm1, 8MB each) alias
  // inter1; Q planes (gemm2, 4MB each) alias inter2.
  ushort* inter1 = (ushort*)(ws);
  ushort* G0     = (ushort*)(ws);
  ushort* G1     = (ushort*)(ws + 8 * MB);
  ushort* inter2 = (ushort*)(ws + 16 * MB);
  ushort* Q0     = (ushort*)(ws + 16 * MB);
  ushort* Q1     = (ushort*)(ws + 20 * MB);
  ushort* Q2     = (ushort*)(ws + 24 * MB);
  ushort* Q3     = (ushort*)(ws + 28 * MB);
  ushort* W1b    = (ushort*)(ws + 32 * MB);
  ushort* W2b    = (ushort*)(ws + 48 * MB);
  ushort* xb     = (ushort*)(ws + 64 * MB);
  ushort* hb     = (ushort*)(ws + 68 * MB);
  char*   S      = ws + 76 * MB;
  float*  t1     = (float*)(S);
  float*  t2     = (float*)(S + 4096);
  float*  b1     = (float*)(S + 8192);
  float*  b2     = (float*)(S + 8192 + 16384);
  float*  parts  = (float*)(S + 8192 + 16384 + 8192);   // 2048 floats

  prep<<<2052, 256, 0, stream>>>((const float4*)x, (ushort4*)xb, V,
                                 BB_W1, BB_W2, t1, t2,
                                 BB_b1, Pi_b1, GG_b1, b1_0,
                                 BB_b2, Pi_b2, GG_b2, b2_0, b1, b2);

  ff_pass1<<<2048, 256, 0, stream>>>(Pi_W1, GG_W1, Pi_W2, GG_W2, t1, t2,
                                     inter1, inter2, parts);
  ff_pass2<<<256, 512, 0, stream>>>(inter1, inter2, W1_0, W2_0, parts, W1b, W2b);

  // gemm1: x @ W1b^T, K=2048 split-K2 -> G0,G1 (512 blocks, 2/CU)
  gemm_sp<16><<<dim3(32, 8, 2), 256, 0, stream>>>(xb, W1b, G0, G1, nullptr, nullptr,
                                                  1024, 4096, 2048);
  // h = relu(G0+G1+b1)
  hfuse<<<4096, 256, 0, stream>>>((const ushort4*)G0, (const ushort4*)G1, b1,
                                  (ushort4*)hb);
  // gemm2: h @ W2b^T, K=4096 split-K4 -> Q0..Q3 (512 blocks, 2/CU)
  gemm_sp<16><<<dim3(16, 8, 4), 256, 0, stream>>>(hb, W2b, Q0, Q1, Q2, Q3,
                                                  1024, 2048, 4096);
  // out = Q0+Q1+Q2+Q3 + b2
  reduce_out4<<<2048, 256, 0, stream>>>((const ushort4*)Q0, (const ushort4*)Q1,
                                        (const ushort4*)Q2, (const ushort4*)Q3,
                                        b2, (float4*)out);
}